// Round 9
// baseline (1049.234 us; speedup 1.0000x reference)
//
#include <hip/hip_runtime.h>
#include <cstddef>
#include <cstdint>

#define DIVUP(a,b) (((a)+(b)-1)/(b))

typedef __attribute__((ext_vector_type(8))) short short8;
typedef __attribute__((ext_vector_type(4))) float f32x4;

__device__ __forceinline__ ushort f2bf(float f) {
    union { float f; uint32_t u; } v; v.f = f;
    uint32_t r = v.u + 0x7fffu + ((v.u >> 16) & 1u);
    return (ushort)(r >> 16);
}

// XCD-chunked block swizzle (kept; neutral on FETCH, cheap).
struct SwzB { int x, y, z; };
__device__ __forceinline__ SwzB swz_block() {
    int gx = gridDim.x, gy = gridDim.y;
    int n = gx * gy * gridDim.z;
    int lin = blockIdx.x + gx * (blockIdx.y + gy * blockIdx.z);
    if ((n & 7) == 0)
        lin = (lin & 7) * (n >> 3) + (lin >> 3);
    SwzB s;
    s.x = lin % gx;
    int t = lin / gx;
    s.y = t % gy;
    s.z = t / gy;
    return s;
}

// ============ fp32 direct conv (small-Cin stride-2 convs: W_ct, W1a), batched ======
template<int COUT, int STRIDE>
__global__ __launch_bounds__(256)
void conv3x3_k(const float* __restrict__ in0, const float* __restrict__ in1,
               const float* __restrict__ wgt, const float* __restrict__ bias,
               float* __restrict__ out, float* __restrict__ stats,
               int Cin, int D, int H, int W, int nz, long out_bs, int st_bs)
{
    constexpr int TD = 4, TH = 8, TW = 8;
    constexpr int ID = 2 * TD + 1, IH = 2 * TH + 1, IW = 2 * TW + 1;
    __shared__ float tile[ID * IH * IW];
    const int b = blockIdx.z / nz, zb = blockIdx.z % nz;
    const float* in = b ? in1 : in0;
    out += (long)b * out_bs;
    if (stats) stats += 2 * st_bs * b;
    const int Do = D / STRIDE, Ho = H / STRIDE, Wo = W / STRIDE;
    const int tid = threadIdx.x;
    const int tw = tid & 7, th = (tid >> 3) & 7, td = tid >> 6;
    const int ow0 = blockIdx.x * TW, oh0 = blockIdx.y * TH, od0 = zb * TD;
    const int iw0 = ow0 * STRIDE - 1, ih0 = oh0 * STRIDE - 1, id0 = od0 * STRIDE - 1;
    const size_t HWs = (size_t)H * W;

    float acc[COUT];
#pragma unroll
    for (int i = 0; i < COUT; i++) acc[i] = 0.f;

    for (int c = 0; c < Cin; ++c) {
        const float* inc = in + (size_t)c * D * HWs;
        for (int i = tid; i < ID * IH * IW; i += 256) {
            int lw = i % IW, lh = (i / IW) % IH, ld = i / (IW * IH);
            int gw = iw0 + lw, gh = ih0 + lh, gd = id0 + ld;
            float v = 0.f;
            if ((unsigned)gw < (unsigned)W && (unsigned)gh < (unsigned)H &&
                (unsigned)gd < (unsigned)D)
                v = inc[(size_t)gd * HWs + (size_t)gh * W + gw];
            tile[i] = v;
        }
        __syncthreads();
        float r[27];
        const int bd = td * STRIDE, bh = th * STRIDE, bw = tw * STRIDE;
#pragma unroll
        for (int kd = 0; kd < 3; kd++)
#pragma unroll
            for (int kh = 0; kh < 3; kh++)
#pragma unroll
                for (int kw = 0; kw < 3; kw++)
                    r[kd * 9 + kh * 3 + kw] =
                        tile[(bd + kd) * (IH * IW) + (bh + kh) * IW + (bw + kw)];
#pragma unroll
        for (int oc = 0; oc < COUT; ++oc) {
            const float* wp = wgt + ((size_t)oc * Cin + c) * 27;
            float s = 0.f;
#pragma unroll
            for (int t = 0; t < 27; t++) s = fmaf(wp[t], r[t], s);
            acc[oc] += s;
        }
        __syncthreads();
    }
    const size_t So = (size_t)Do * Ho * Wo;
    const size_t sp = (size_t)(od0 + td) * Ho * Wo + (size_t)(oh0 + th) * Wo + (ow0 + tw);
#pragma unroll
    for (int oc = 0; oc < COUT; ++oc)
        out[(size_t)oc * So + sp] = acc[oc] + bias[oc];

    if (stats) {
        __syncthreads();
        float* sm = tile;
        const int wv = tid >> 6, l = tid & 63;
#pragma unroll
        for (int oc = 0; oc < COUT; ++oc) {
            float sv = acc[oc] + bias[oc];
            float sq = sv * sv;
#pragma unroll
            for (int o = 32; o > 0; o >>= 1) {
                sv += __shfl_down(sv, o, 64);
                sq += __shfl_down(sq, o, 64);
            }
            if (l == 0) { sm[(wv * COUT + oc) * 2] = sv; sm[(wv * COUT + oc) * 2 + 1] = sq; }
        }
        __syncthreads();
        if (tid < COUT) {
            float s = 0.f, s2 = 0.f;
#pragma unroll
            for (int w = 0; w < 4; ++w) {
                s += sm[(w * COUT + tid) * 2];
                s2 += sm[(w * COUT + tid) * 2 + 1];
            }
            atomicAdd(&stats[2 * tid], s);
            atomicAdd(&stats[2 * tid + 1], s2);
        }
    }
}

// ============ MFMA implicit-GEMM conv (fused stats, batched) =================
// Weight layout (wprep kind 0): [kc][kd][kh][kw][nf][512].
// STRIDE==1: per-kd weight slices double-buffered in LDS (round-4 mechanism).
// KC>1 additionally reg-prefetches the NEXT kc's halo in two halves issued
// after barriers 1/2 — each half's HBM latency hides under one compute phase,
// removing the serial halo drain at each kc head (round-8 theory). KC==1 keeps
// the plain gll halo stage (no cross-kc pipeline exists; round-7 lesson: don't
// graft mechanisms where the coupling is absent). STRIDE==2 unchanged.
template<int CP, int NF, int STRIDE, int MW, int COUTR>
__global__ __launch_bounds__(MW * 64, (STRIDE == 1) ? 2 : 4)
void mconv_k(const ushort* __restrict__ xcl, const ushort* __restrict__ wp,
             const float* __restrict__ bias, float* __restrict__ outcf,
             float* __restrict__ stats, const ushort* __restrict__ zbuf,
             int D, int H, int W, int nz, long in_bs, long out_bs, int st_bs)
{
    constexpr int KC = CP / 32;
    constexpr int MF = (STRIDE == 1) ? 4 : 1;
    constexpr int TD = MW;
    constexpr int TWl = (STRIDE == 1) ? 8 : 4;
    constexpr int HD = (STRIDE == 1) ? TD + 2 : 2 * TD + 1;
    constexpr int HH = (STRIDE == 1) ? 10 : 9;
    constexpr int HWd = (STRIDE == 1) ? 10 : 9;
    constexpr int HALO = HD * HH * HWd;
    constexpr int NTH = MW * 64;
    constexpr int NIT = (HALO * 4 + NTH - 1) / NTH;
    constexpr int PITCH = (STRIDE == 1) ? 32 : 40;   // ushorts per point
    constexpr int LDSZ_H = (STRIDE == 1) ? NIT * NTH * 8 : HALO * 40;
    constexpr int NITW = (9 * NF * 512 + NTH * 8 - 1) / (NTH * 8);    // per-kd (s1)
    constexpr int LDSZ_W = NITW * NTH * 8;
    constexpr int LDS_TOT = (STRIDE == 1) ? LDSZ_H + 2 * LDSZ_W : LDSZ_H;
    __shared__ __align__(16) ushort lds[LDS_TOT];

    const int tid = threadIdx.x;
    const int wv = tid >> 6, l = tid & 63;
    const SwzB sb = swz_block();
    const int b = sb.z / nz, zb = sb.z % nz;
    xcl += (long)b * in_bs;
    outcf += (long)b * out_bs;
    if (stats) stats += 2 * st_bs * b;
    const int od0 = zb * TD, oh0 = sb.y * ((STRIDE == 1) ? 8 : 4),
              ow0 = sb.x * TWl;
    const int id0 = od0 * STRIDE - 1, ih0 = oh0 * STRIDE - 1, iw0 = ow0 * STRIDE - 1;

    f32x4 acc[MF][NF];
#pragma unroll
    for (int mf = 0; mf < MF; mf++)
#pragma unroll
        for (int nf = 0; nf < NF; nf++) acc[mf][nf] = f32x4{0.f, 0.f, 0.f, 0.f};

    auto woff = [&](int kc, int kd, int kh, int kw, int nf) -> size_t {
        return ((((size_t)(kc * 3 + kd) * 3 + kh) * 3 + kw) * NF + nf) << 9;
    };

    if constexpr (STRIDE == 1) {
        ushort* const hab = lds;
        ushort* const wbA = lds + LDSZ_H;
        ushort* const wbB = lds + LDSZ_H + LDSZ_W;

        auto wstage = [&](int kc, int kd, ushort* dst) {
#pragma unroll
            for (int it = 0; it < NITW; ++it) {
                int idx = it * NTH + tid;
                const ushort* src = (idx < 9 * NF * 64)
                    ? wp + ((size_t)(kc * 3 + kd) * 9 * NF * 512 + (size_t)idx * 8)
                    : zbuf;
                __builtin_amdgcn_global_load_lds(
                    (const __attribute__((address_space(1))) uint32_t*)src,
                    (__attribute__((address_space(3))) uint32_t*)
                        &dst[(size_t)(it * NTH + (wv << 6)) * 8],
                    16, 0, 0);
            }
        };
        auto compute = [&](int kd, const ushort* w) {
#pragma unroll
            for (int kw = 0; kw < 3; ++kw) {
                short8 af[9];
#pragma unroll
                for (int r = 0; r < 9; ++r)
                    af[r] = *reinterpret_cast<const short8*>(
                        &hab[((wv + kd) * (HH * HWd) +
                              (r + ((l >> 3) & 1)) * HWd + (l & 7) + kw) * PITCH +
                             ((l >> 4) << 3)]);
#pragma unroll
                for (int kh = 0; kh < 3; ++kh) {
                    short8 bf[NF];
#pragma unroll
                    for (int nf = 0; nf < NF; ++nf)
                        bf[nf] = *reinterpret_cast<const short8*>(
                            &w[(size_t)(((kh * 3 + kw) * NF) + nf) * 512 + (l << 3)]);
#pragma unroll
                    for (int mf = 0; mf < MF; ++mf)
#pragma unroll
                        for (int nf = 0; nf < NF; ++nf)
                            acc[mf][nf] = __builtin_amdgcn_mfma_f32_16x16x32_bf16(
                                af[2 * mf + kh], bf[nf], acc[mf][nf], 0, 0, 0);
                }
            }
        };

        if constexpr (KC == 1) {
            // single-kc: plain gll halo stage (no pipeline possible)
#pragma unroll
            for (int it = 0; it < NIT; ++it) {
                int idx = it * NTH + tid;
                int pt = idx >> 2, part = idx & 3;
                int lw = pt % HWd, lh = (pt / HWd) % HH, ld = pt / (HWd * HH);
                int gx = iw0 + lw, gy = ih0 + lh, gz = id0 + ld;
                const ushort* src = zbuf;
                if (pt < HALO && (unsigned)gx < (unsigned)W &&
                    (unsigned)gy < (unsigned)H && (unsigned)gz < (unsigned)D)
                    src = xcl + (size_t)((gz * H + gy) * W + gx) * CP + part * 8;
                __builtin_amdgcn_global_load_lds(
                    (const __attribute__((address_space(1))) uint32_t*)src,
                    (__attribute__((address_space(3))) uint32_t*)
                        &hab[(size_t)(it * NTH + (wv << 6)) * 8],
                    16, 0, 0);
            }
            wstage(0, 0, wbA);
            __syncthreads();
            wstage(0, 1, wbB);
            compute(0, wbA);
            __syncthreads();
            wstage(0, 2, wbA);
            compute(1, wbB);
            __syncthreads();
            compute(2, wbA);
            __syncthreads();
        } else {
            uint4 v[NIT];
            auto hfetch = [&](int kc, int lo, int hi) {
#pragma unroll
                for (int it = 0; it < NIT; ++it) {
                    if (it < lo || it >= hi) continue;
                    int idx = it * NTH + tid;
                    int pt = idx >> 2, part = idx & 3;
                    int lw = pt % HWd, lh = (pt / HWd) % HH, ld = pt / (HWd * HH);
                    int gx = iw0 + lw, gy = ih0 + lh, gz = id0 + ld;
                    uint4 t = {0u, 0u, 0u, 0u};
                    if (pt < HALO && (unsigned)gx < (unsigned)W &&
                        (unsigned)gy < (unsigned)H && (unsigned)gz < (unsigned)D)
                        t = *reinterpret_cast<const uint4*>(
                            xcl + (size_t)((gz * H + gy) * W + gx) * CP + kc * 32 + part * 8);
                    v[it] = t;
                }
            };
            auto hwrite = [&]() {
#pragma unroll
                for (int it = 0; it < NIT; ++it)
                    *reinterpret_cast<uint4*>(&lds[(size_t)(it * NTH + tid) * 8]) = v[it];
            };
            constexpr int NH = NIT / 2;

            hfetch(0, 0, NIT);                    // prologue (serial, once)
            for (int kc = 0; kc < KC; ++kc) {
                hwrite();                         // regs -> halo LDS
                wstage(kc, 0, wbA);
                __syncthreads();                  // halo visible + w0 landed
                if (kc + 1 < KC) hfetch(kc + 1, 0, NH);   // half A under compute0
                wstage(kc, 1, wbB);
                compute(0, wbA);
                __syncthreads();                  // w1 landed (+half A drained)
                if (kc + 1 < KC) hfetch(kc + 1, NH, NIT); // half B under compute1
                wstage(kc, 2, wbA);
                compute(1, wbB);
                __syncthreads();                  // w2 landed (+half B drained)
                compute(2, wbA);
                __syncthreads();                  // done reading hab/wbA
            }
        }
    } else {
        uint4 v[NIT];
        auto stage = [&](int kc) {
#pragma unroll
            for (int it = 0; it < NIT; ++it) {
                int idx = it * NTH + tid;
                uint4 t = {0u, 0u, 0u, 0u};
                if (idx < HALO * 4) {
                    int pt = idx >> 2, part = idx & 3;
                    int lw = pt % HWd, lh = (pt / HWd) % HH, ld = pt / (HWd * HH);
                    int gx = iw0 + lw, gy = ih0 + lh, gz = id0 + ld;
                    if ((unsigned)gx < (unsigned)W && (unsigned)gy < (unsigned)H &&
                        (unsigned)gz < (unsigned)D)
                        t = *reinterpret_cast<const uint4*>(
                            xcl + ((size_t)((gz * H + gy) * W + gx)) * CP + kc * 32 + part * 8);
                }
                v[it] = t;
            }
        };

        stage(0);
        for (int kc = 0; kc < KC; ++kc) {
            if (kc) __syncthreads();
#pragma unroll
            for (int it = 0; it < NIT; ++it) {
                int idx = it * NTH + tid;
                if (idx < HALO * 4)
                    *reinterpret_cast<uint4*>(&lds[(idx >> 2) * PITCH + (idx & 3) * 8]) = v[it];
            }
            __syncthreads();
            if (kc + 1 < KC) stage(kc + 1);
#pragma unroll
            for (int t = 0; t < 27; ++t) {
                const int kd = t / 9, kh = (t / 3) % 3, kw = t % 3;
                short8 bf[NF];
#pragma unroll
                for (int nf = 0; nf < NF; ++nf)
                    bf[nf] = *reinterpret_cast<const short8*>(
                        wp + woff(kc, kd, kh, kw, nf) + (l << 3));
                int bw = l & 3, bh = (l >> 2) & 3;
                int p_loc = (2 * wv + kd) * (HH * HWd) + (2 * bh + kh) * HWd + (2 * bw + kw);
                short8 afs = *reinterpret_cast<const short8*>(&lds[p_loc * PITCH + ((l >> 4) << 3)]);
#pragma unroll
                for (int nf = 0; nf < NF; ++nf)
                    acc[0][nf] = __builtin_amdgcn_mfma_f32_16x16x32_bf16(
                        afs, bf[nf], acc[0][nf], 0, 0, 0);
            }
        }
    }
    const int Do = D / STRIDE, Ho = H / STRIDE, Wo = W / STRIDE;
    const size_t So = (size_t)Do * Ho * Wo;
    float ps[NF], ps2[NF];
#pragma unroll
    for (int nf = 0; nf < NF; ++nf) { ps[nf] = 0.f; ps2[nf] = 0.f; }
#pragma unroll
    for (int nf = 0; nf < NF; ++nf) {
        int oc = nf * 16 + (l & 15);
        float bv = (oc < COUTR) ? bias[oc] : 0.f;
#pragma unroll
        for (int mf = 0; mf < MF; ++mf) {
#pragma unroll
            for (int r = 0; r < 4; ++r) {
                int q = ((l >> 4) << 2) + r;
                int bw, bh;
                if (STRIDE == 1) { bw = q & 7; bh = 2 * mf + (q >> 3); }
                else             { bw = q & 3; bh = (q >> 2) & 3; }
                int p = ((od0 + wv) * Ho + (oh0 + bh)) * Wo + (ow0 + bw);
                float val = acc[mf][nf][r] + bv;
                if (oc < COUTR) {
                    outcf[(size_t)oc * So + p] = val;
                    ps[nf] += val; ps2[nf] = fmaf(val, val, ps2[nf]);
                }
            }
        }
    }
    if (stats) {
        __syncthreads();
        float* sm = (float*)lds;
#pragma unroll
        for (int nf = 0; nf < NF; ++nf) {
            float s = ps[nf], s2 = ps2[nf];
            s += __shfl_down(s, 32, 64);  s2 += __shfl_down(s2, 32, 64);
            s += __shfl_down(s, 16, 64);  s2 += __shfl_down(s2, 16, 64);
            if (l < 16) {
                sm[((wv * NF + nf) * 16 + l) * 2] = s;
                sm[((wv * NF + nf) * 16 + l) * 2 + 1] = s2;
            }
        }
        __syncthreads();
        if (tid < NF * 16) {
            int nf = tid >> 4, c = tid & 15, oc = nf * 16 + c;
            if (oc < COUTR) {
                float s = 0.f, s2 = 0.f;
#pragma unroll
                for (int w = 0; w < MW; ++w) {
                    s += sm[((w * NF + nf) * 16 + c) * 2];
                    s2 += sm[((w * NF + nf) * 16 + c) * 2 + 1];
                }
                atomicAdd(&stats[2 * oc], s);
                atomicAdd(&stats[2 * oc + 1], s2);
            }
        }
    }
}

// ======================= consolidated weight prep ============================
struct WTask { const float* src; void* dst; int kind, Cin, COUT, KC, coutr, base; };
struct WTab { WTask t[17]; int n; };

__global__ __launch_bounds__(256)
void wprep_k(WTab tab)
{
    int b = blockIdx.x, ti = 0;
    for (int i = 0; i < tab.n; ++i) if (b >= tab.t[i].base) ti = i;
    const WTask tk = tab.t[ti];
    int idx = (b - tk.base) * 256 + threadIdx.x;
    if (tk.kind == 0) {
        // layout: [kc][kd][kh][kw][nf][512]
        int NF = tk.COUT >> 4;
        int tot = 27 * tk.KC * NF * 512;
        if (idx >= tot) return;
        int j = idx & 7, l = (idx >> 3) & 63;
        int g = idx >> 9;
        int nf = g % NF; g /= NF;
        int kw = g % 3; g /= 3;
        int kh = g % 3; g /= 3;
        int kd = g % 3; int kc = g / 3;
        int t = kd * 9 + kh * 3 + kw;
        int oc = nf * 16 + (l & 15);
        int c = kc * 32 + ((l >> 4) << 3) + j;
        float v = (c < tk.Cin && oc < tk.coutr)
                      ? tk.src[((size_t)oc * tk.Cin + c) * 27 + t] : 0.f;
        ((ushort*)tk.dst)[idx] = f2bf(v);
    } else if (tk.kind == 1) {
        int NF = tk.KC;
        int tot = 8 * 8 * NF * 512;
        if (idx >= tot) return;
        int j = idx & 7, l = (idx >> 3) & 63;
        int g = idx >> 9;
        int nf = g % NF; g /= NF;
        int t = g % 8; int pp = g / 8;
        int oc = nf * 16 + (l & 15);
        int c = ((l >> 4) << 3) + j;
        int kd_ = (t >> 2) & 1, kh_ = (t >> 1) & 1, kw_ = t & 1;
        int pd = (pp >> 2) & 1, ph = (pp >> 1) & 1, pw = pp & 1;
        int kd = 3 - pd - 2 * kd_, kh = 3 - ph - 2 * kh_, kw = 3 - pw - 2 * kw_;
        float v = (oc < tk.COUT)
                      ? tk.src[(size_t)(c * tk.COUT + oc) * 64 + kd * 16 + kh * 4 + kw] : 0.f;
        ((ushort*)tk.dst)[idx] = f2bf(v);
    } else {
        int tot = tk.Cin * tk.COUT * 64;
        if (idx >= tot) return;
        int k = idx & 63; int oc = (idx >> 6) % tk.COUT; int c = (idx >> 6) / tk.COUT;
        ((float*)tk.dst)[((size_t)c * 64 + k) * tk.COUT + oc] = tk.src[idx];
    }
}

// ======================= MFMA deconv (uf1) =======================
template<int NF>
__global__ __launch_bounds__(256)
void mdeconv_k(const ushort* __restrict__ xcl, const ushort* __restrict__ wpd,
               const float* __restrict__ bias, ushort* __restrict__ outcl,
               int c0, int CPo, int Si)
{
    constexpr int HD = 5, HH = 9, HWd = 9, HALO = HD * HH * HWd;
    constexpr int PITCH = 32;
    __shared__ __align__(16) ushort lds[HALO * PITCH];
    const int tid = threadIdx.x, wv = tid >> 6, l = tid & 63;
    const SwzB sb = swz_block();
    const int pp = sb.z & 7, tz = sb.z >> 3;
    const int pd = (pp >> 2) & 1, ph = (pp >> 1) & 1, pw = pp & 1;
    const int oz0 = tz * 4, oy0 = sb.y * 8, ox0 = sb.x * 8;
    const int iz0 = oz0 + pd - 1, iy0 = oy0 + ph - 1, ix0 = ox0 + pw - 1;

    for (int idx = tid; idx < HALO * 4; idx += 256) {
        int pt = idx >> 2, part = idx & 3;
        int lw = pt % HWd, lh = (pt / HWd) % HH, ld = pt / (HWd * HH);
        int gx = ix0 + lw, gy = iy0 + lh, gz = iz0 + ld;
        uint4 t = {0u, 0u, 0u, 0u};
        if ((unsigned)gx < (unsigned)Si && (unsigned)gy < (unsigned)Si &&
            (unsigned)gz < (unsigned)Si)
            t = *reinterpret_cast<const uint4*>(
                xcl + ((size_t)((gz * Si + gy) * Si + gx)) * 32 + part * 8);
        *reinterpret_cast<uint4*>(&lds[pt * PITCH + part * 8]) = t;
    }
    __syncthreads();

    f32x4 acc[4][NF];
#pragma unroll
    for (int mf = 0; mf < 4; mf++)
#pragma unroll
        for (int nf = 0; nf < NF; nf++) acc[mf][nf] = f32x4{0.f, 0.f, 0.f, 0.f};

#pragma unroll
    for (int kd = 0; kd < 2; ++kd) {
#pragma unroll
        for (int kw = 0; kw < 2; ++kw) {
            short8 af[8];
#pragma unroll
            for (int r = 0; r < 8; ++r)
                af[r] = *reinterpret_cast<const short8*>(
                    &lds[((wv + kd) * (HH * HWd) + (r + ((l >> 3) & 1)) * HWd +
                          (l & 7) + kw) * PITCH + ((l >> 4) << 3)]);
#pragma unroll
            for (int kh = 0; kh < 2; ++kh) {
                const int t = kd * 4 + kh * 2 + kw;
                short8 bf[NF];
#pragma unroll
                for (int nf = 0; nf < NF; ++nf)
                    bf[nf] = *reinterpret_cast<const short8*>(
                        wpd + (((size_t)(pp * 8 + t) * NF + nf) << 9) + (l << 3));
#pragma unroll
                for (int mf = 0; mf < 4; ++mf)
#pragma unroll
                    for (int nf = 0; nf < NF; ++nf)
                        acc[mf][nf] = __builtin_amdgcn_mfma_f32_16x16x32_bf16(
                            af[2 * mf + kh], bf[nf], acc[mf][nf], 0, 0, 0);
            }
        }
    }
    const int Do = 2 * Si;
#pragma unroll
    for (int nf = 0; nf < NF; ++nf) {
        int oc = nf * 16 + (l & 15);
        float bv = bias[oc];
#pragma unroll
        for (int mf = 0; mf < 4; ++mf) {
#pragma unroll
            for (int r = 0; r < 4; ++r) {
                int q = ((l >> 4) << 2) + r;
                int bw = q & 7, bh = 2 * mf + (q >> 3);
                int oD = 2 * (oz0 + wv) + pd, oH = 2 * (oy0 + bh) + ph, oW = 2 * (ox0 + bw) + pw;
                outcl[(size_t)((oD * Do + oH) * Do + oW) * CPo + c0 + oc] =
                    f2bf(acc[mf][nf][r] + bv);
            }
        }
    }
}

// ======================= output-centric small deconv (COUT=3) ====
template<int CIN>
__global__ __launch_bounds__(256)
void dctn_k(const float* __restrict__ in, const float* __restrict__ wt,
            const float* __restrict__ bias, float* __restrict__ outcf,
            ushort* __restrict__ outcl, int c0, int CPo, int Si)
{
    const int Do = 2 * Si;
    const size_t So = (size_t)Do * Do * Do, ni = (size_t)Si * Si * Si;
    size_t p = (size_t)blockIdx.x * 256 + threadIdx.x;
    if (p >= So) return;
    int oxW = (int)(p % Do), oyH = (int)((p / Do) % Do), ozD = (int)(p / ((size_t)Do * Do));
    int pw = oxW & 1, ph = oyH & 1, pd = ozD & 1;
    int xb = oxW >> 1, yb = oyH >> 1, zb = ozD >> 1;
    float acc[3] = {0.f, 0.f, 0.f};
    for (int c = 0; c < CIN; ++c) {
        const float* inc = in + (size_t)c * ni;
        const float* wc = wt + (size_t)c * 64 * 3;
#pragma unroll
        for (int jd = 0; jd < 2; jd++) {
            int iz = zb + pd - jd; if ((unsigned)iz >= (unsigned)Si) continue;
            int kd = 1 - pd + 2 * jd;
#pragma unroll
            for (int jh = 0; jh < 2; jh++) {
                int iy = yb + ph - jh; if ((unsigned)iy >= (unsigned)Si) continue;
                int kh = 1 - ph + 2 * jh;
#pragma unroll
                for (int jw = 0; jw < 2; jw++) {
                    int ix = xb + pw - jw; if ((unsigned)ix >= (unsigned)Si) continue;
                    int kw = 1 - pw + 2 * jw;
                    float v = inc[((size_t)iz * Si + iy) * Si + ix];
                    const float* wr = wc + (size_t)((kd * 4 + kh) * 4 + kw) * 3;
                    acc[0] = fmaf(wr[0], v, acc[0]);
                    acc[1] = fmaf(wr[1], v, acc[1]);
                    acc[2] = fmaf(wr[2], v, acc[2]);
                }
            }
        }
    }
#pragma unroll
    for (int oc = 0; oc < 3; ++oc) {
        float o = acc[oc] + bias[oc];
        if (outcf) outcf[(size_t)oc * So + p] = o;
        if (outcl) outcl[p * CPo + c0 + oc] = f2bf(o);
    }
}

// ============ instance norm apply (batched ycl via Cper; optional ch-last f32) =====
__global__ __launch_bounds__(256)
void inorm_apply_k(const float* __restrict__ x, const float* __restrict__ stats,
                   float* __restrict__ y, size_t S, float invS,
                   ushort* __restrict__ ycl, int CP, int Cper, long ycl_bs,
                   float* __restrict__ yclf, int CPf, int Cf)
{
    int c = blockIdx.y;
    float sum = stats[2 * c], ss = stats[2 * c + 1];
    float m = sum * invS;
    float r = rsqrtf(fmaxf(ss * invS - m * m, 0.f) + 1e-5f);
    size_t i = (size_t)blockIdx.x * 256 + threadIdx.x;
    if (i >= S) return;
    float v = (x[(size_t)c * S + i] - m) * r;
    v = v >= 0.f ? v : 0.1f * v;
    y[(size_t)c * S + i] = v;
    if (ycl) {
        int b = c / Cper, cl = c - b * Cper;
        ycl[(long)b * ycl_bs + (long)i * CP + cl] = f2bf(v);
    }
    if (yclf && c < Cf)
        yclf[i * (size_t)CPf + c] = v;
}

// ======================= cost volume (ch-major, stage-2 only) =========
template<int C, int CP, int COPYC>
__global__ __launch_bounds__(256)
void costvolw_k(const float* __restrict__ f1, const float* __restrict__ f2,
                ushort* __restrict__ outcl, int D, int H, int W)
{
    const size_t S = (size_t)D * H * W;
    size_t p = (size_t)blockIdx.x * 4 + (threadIdx.x >> 6);
    if (p >= S) return;
    const int l = threadIdx.x & 63;
    int x = (int)(p % W); int y = (int)((p / W) % H); int z = (int)(p / ((size_t)W * H));
    float a[C];
#pragma unroll
    for (int c = 0; c < C; c++) a[c] = f1[(size_t)c * S + p];
    const float inv = 1.f / C;
    ushort* op = outcl + p * CP;
#pragma unroll
    for (int rep = 0; rep < 2; rep++) {
        int s = l + rep * 64;
        if (s < 125) {
            int v = s / 25 - 2, h = (s / 5) % 5 - 2, d = s % 5 - 2;
            int zz = z + v, yy = y + h, xx = x + d;
            float acc = 0.f;
            if ((unsigned)zz < (unsigned)D && (unsigned)yy < (unsigned)H &&
                (unsigned)xx < (unsigned)W) {
                size_t q = ((size_t)zz * H + yy) * (size_t)W + xx;
#pragma unroll
                for (int c = 0; c < C; c++) acc = fmaf(a[c], f2[(size_t)c * S + q], acc);
            }
            acc *= inv;
            op[s] = f2bf(acc >= 0.f ? acc : 0.1f * acc);
        }
    }
    if (COPYC && l < C)
        op[125 + l] = f2bf(f1[(size_t)l * S + p]);
}

// ============ cost volume, channel-last fp32 operands, NP points/wave ============
template<int C, int CP, int NP>
__global__ __launch_bounds__(256)
void costvolcl_k(const float* __restrict__ f1cl, const float* __restrict__ f2cl,
                 ushort* __restrict__ outcl, int D, int H, int W)
{
    const size_t S = (size_t)D * H * W;
    size_t p0 = ((size_t)blockIdx.x * 4 + (threadIdx.x >> 6)) * NP;
    if (p0 >= S) return;
    const int l = threadIdx.x & 63;
    float a[NP][C];
#pragma unroll
    for (int pp = 0; pp < NP; pp++)
#pragma unroll
        for (int c4 = 0; c4 < C / 4; c4++) {
            float4 t = *reinterpret_cast<const float4*>(&f1cl[(p0 + pp) * C + c4 * 4]);
            a[pp][c4 * 4 + 0] = t.x; a[pp][c4 * 4 + 1] = t.y;
            a[pp][c4 * 4 + 2] = t.z; a[pp][c4 * 4 + 3] = t.w;
        }
    const float inv = 1.f / C;
#pragma unroll
    for (int rep = 0; rep < 2; rep++) {
        int s = l + rep * 64;
        int v = s / 25 - 2, h = (s / 5) % 5 - 2, d = s % 5 - 2;
        bool sv = s < 125;
#pragma unroll
        for (int pp = 0; pp < NP; pp++) {
            size_t p = p0 + pp;
            int x = (int)(p % W), y = (int)((p / W) % H), z = (int)(p / ((size_t)W * H));
            int zz = z + v, yy = y + h, xx = x + d;
            float acc = 0.f;
            if (sv && (unsigned)zz < (unsigned)D && (unsigned)yy < (unsigned)H &&
                (unsigned)xx < (unsigned)W) {
                size_t q = ((size_t)zz * H + yy) * (size_t)W + xx;
#pragma unroll
                for (int c4 = 0; c4 < C / 4; c4++) {
                    float4 b = *reinterpret_cast<const float4*>(&f2cl[q * C + c4 * 4]);
                    acc = fmaf(a[pp][c4 * 4 + 0], b.x, acc);
                    acc = fmaf(a[pp][c4 * 4 + 1], b.y, acc);
                    acc = fmaf(a[pp][c4 * 4 + 2], b.z, acc);
                    acc = fmaf(a[pp][c4 * 4 + 3], b.w, acc);
                }
            }
            if (sv) {
                acc *= inv;
                outcl[p * CP + s] = f2bf(acc >= 0.f ? acc : 0.1f * acc);
            }
        }
    }
    if (l < C) {
#pragma unroll
        for (int pp = 0; pp < NP; pp++)
            outcl[(p0 + pp) * CP + 125 + l] = f2bf(f1cl[(p0 + pp) * C + l]);
    }
}

// ======================= trilinear warp (clamped), channel-last out ===========
template<int C>
__global__ __launch_bounds__(256)
void warpcl_k(const float* __restrict__ img, const float* __restrict__ flow,
              float* __restrict__ outcl, int D, int H, int W)
{
    const size_t S = (size_t)D * H * W;
    size_t p = (size_t)blockIdx.x * 256 + threadIdx.x;
    if (p >= S) return;
    int x = (int)(p % W); int y = (int)((p / W) % H); int z = (int)(p / ((size_t)W * H));
    float cd = fminf(fmaxf((float)z + flow[p], 0.f), (float)(D - 1));
    float ch = fminf(fmaxf((float)y + flow[S + p], 0.f), (float)(H - 1));
    float cw = fminf(fmaxf((float)x + flow[2 * S + p], 0.f), (float)(W - 1));
    int d0 = (int)cd, h0 = (int)ch, w0 = (int)cw;
    float fd = cd - d0, fh = ch - h0, fw = cw - w0;
    int d1 = min(d0 + 1, D - 1), h1 = min(h0 + 1, H - 1), w1 = min(w0 + 1, W - 1);
    size_t i000 = ((size_t)d0 * H + h0) * W + w0, i001 = ((size_t)d0 * H + h0) * W + w1;
    size_t i010 = ((size_t)d0 * H + h1) * W + w0, i011 = ((size_t)d0 * H + h1) * W + w1;
    size_t i100 = ((size_t)d1 * H + h0) * W + w0, i101 = ((size_t)d1 * H + h0) * W + w1;
    size_t i110 = ((size_t)d1 * H + h1) * W + w0, i111 = ((size_t)d1 * H + h1) * W + w1;
    float w000 = (1 - fd) * (1 - fh) * (1 - fw), w001 = (1 - fd) * (1 - fh) * fw;
    float w010 = (1 - fd) * fh * (1 - fw),       w011 = (1 - fd) * fh * fw;
    float w100 = fd * (1 - fh) * (1 - fw),       w101 = fd * (1 - fh) * fw;
    float w110 = fd * fh * (1 - fw),             w111 = fd * fh * fw;
#pragma unroll
    for (int c4 = 0; c4 < C / 4; c4++) {
        float4 r;
        float* rr = reinterpret_cast<float*>(&r);
#pragma unroll
        for (int j = 0; j < 4; j++) {
            const float* ic = img + (size_t)(c4 * 4 + j) * S;
            rr[j] = w000 * ic[i000] + w001 * ic[i001] + w010 * ic[i010] + w011 * ic[i011]
                  + w100 * ic[i100] + w101 * ic[i101] + w110 * ic[i110] + w111 * ic[i111];
        }
        *reinterpret_cast<float4*>(&outcl[p * C + c4 * 4]) = r;
    }
}

// ======================= host orchestration =======================
static void apply(hipStream_t st, float* x, int C, size_t S, const float* stats,
                  ushort* ycl, int CP, int Cper, long ycl_bs,
                  float* yclf = nullptr, int CPf = 0, int Cf = 0)
{
    dim3 g((unsigned)DIVUP(S, 256), C);
    inorm_apply_k<<<g, 256, 0, st>>>(x, stats, x, S, 1.0f / (float)S, ycl, CP, Cper, ycl_bs,
                                     yclf, CPf, Cf);
}

extern "C" void kernel_launch(void* const* d_in, const int* in_sizes, int n_in,
                              void* d_out, int out_size, void* d_ws, size_t ws_size,
                              hipStream_t st)
{
    (void)in_sizes; (void)n_in; (void)out_size; (void)ws_size;
    const float* atlas  = (const float*)d_in[0];
    const float* target = (const float*)d_in[1];
    const float *W_ct = (const float*)d_in[2],  *b_ct = (const float*)d_in[3];
    const float *W1a  = (const float*)d_in[4],  *b1a  = (const float*)d_in[5];
    const float *W1aa = (const float*)d_in[6],  *b1aa = (const float*)d_in[7];
    const float *W1b  = (const float*)d_in[8],  *b1b  = (const float*)d_in[9];
    const float *W2a  = (const float*)d_in[10], *b2a  = (const float*)d_in[11];
    const float *W2aa = (const float*)d_in[12], *b2aa = (const float*)d_in[13];
    const float *W2b  = (const float*)d_in[14], *b2b  = (const float*)d_in[15];
    const float *W20  = (const float*)d_in[16], *b20  = (const float*)d_in[17];
    const float *Wpf2 = (const float*)d_in[18], *bpf2 = (const float*)d_in[19];
    const float *Wd2  = (const float*)d_in[20], *bd2  = (const float*)d_in[21];
    const float *Wuf2 = (const float*)d_in[22], *buf2 = (const float*)d_in[23];
    const float *W10  = (const float*)d_in[24], *b10  = (const float*)d_in[25];
    const float *Wpf1 = (const float*)d_in[26], *bpf1 = (const float*)d_in[27];
    const float *Wd1  = (const float*)d_in[28], *bd1  = (const float*)d_in[29];
    const float *Wuf1 = (const float*)d_in[30], *buf1 = (const float*)d_in[31];
    const float *W00  = (const float*)d_in[32], *b00  = (const float*)d_in[33];
    const float *Wpf0 = (const float*)d_in[34], *bpf0 = (const float*)d_in[35];
    const float *Wd0  = (const float*)d_in[36], *bd0  = (const float*)d_in[37];

    const size_t S128 = 128u * 128 * 128, S64 = 64u * 64 * 64, S32 = 32u * 32 * 32, S16 = 16u * 16 * 16;

    char* base = (char*)d_ws;
    size_t off = 0;
    auto AF = [&](size_t n) { off = (off + 255) & ~(size_t)255; float* p = (float*)(base + off); off += n * 4; return p; };
    auto AH = [&](size_t n) { off = (off + 255) & ~(size_t)255; ushort* p = (ushort*)(base + off); off += n * 2; return p; };

    ushort* wp1aa = AH(13824); ushort* wp1b = AH(13824);
    ushort* wp2a  = AH(27648); ushort* wp2aa = AH(27648); ushort* wp2b = AH(27648);
    ushort* wp20  = AH(110592); ushort* wp10 = AH(138240); ushort* wp00 = AH(193536);
    ushort* wpf2  = AH(13824);  ushort* wpf1 = AH(13824);  ushort* wpf0 = AH(13824);
    ushort* wpd_uf1 = AH(131072);
    float* wt_uf2 = AF(6144);
    float* wt_d2  = AF(576);    float* wt_d1 = AF(576);    float* wt_d0 = AF(576);
    float* stats = AF(1024);
    ushort* zbuf = AH(1024);    // zero guard for OOB global_load_lds sources
    float* im12 = AF(8 * S64);
    float* im1 = im12; float* im2 = im12 + 4 * S64;
    float* im1clf = AF(4 * S64);     // [S64][4] ch-last fp32 (costvol E f1)
    float* warp0clf = AF(4 * S64);   // [S64][4] ch-last fp32 (costvol E f2)
    float* c11clf = AF(16 * S32);    // [S32][16] ch-last fp32 (costvol D f1)
    float* warp1clf = AF(16 * S32);  // [S32][16] ch-last fp32 (costvol D f2)
    float* A1   = AF(32 * S32); ushort* A1cl = AH(2 * S32 * 32);
    float* B1   = AF(32 * S32); ushort* B1cl = AH(2 * S32 * 32);
    float* c1121 = AF(32 * S32); ushort* c1121cl = AH(2 * S32 * 32);
    float* c11 = c1121; float* c21 = c1121 + 16 * S32;
    float* A2   = AF(64 * S16); ushort* A2cl = AH(2 * S16 * 32);
    float* B2   = AF(64 * S16); ushort* B2cl = AH(2 * S16 * 32);
    ushort* cv2cl = AH(S16 * 128);
    float* x20  = AF(32 * S16); ushort* x20cl = AH(S16 * 32);
    float* flow2 = AF(3 * S16); float* upflow2 = AF(3 * S32);
    ushort* x147cl = AH(S32 * 160);
    float* x10  = AF(32 * S32); ushort* x10cl = AH(S32 * 32);
    float* flow1 = AF(3 * S32); float* upflow1 = AF(3 * S64);
    ushort* x196cl = AH(S64 * 224);
    float* x00  = AF(32 * S64); float* flow0 = AF(3 * S64);

    ushort* x00cl = x196cl;            // overlay: live only after W00 consumed x196cl

    float* outF = (float*)d_out;
    float* c22o = outF + 3 * S128;
    float* c12o = c22o + 32 * S16;

    // stats layout: batched pairs contiguous
    const int ST_IM=0, ST_A1=8, ST_B1=40, ST_C1=72, ST_A2=104, ST_B2=168, ST_C2=232,
              ST_X20=296, ST_X10=328, ST_X00=360;
    auto SP = [&](int o) { return stats + 2 * o; };
    hipMemsetAsync(stats, 0, 4096, st);
    hipMemsetAsync(zbuf, 0, 2048, st);

    WTab tab; int nb = 0, ti = 0;
    auto addw = [&](const float* s, void* d, int kind, int Cin, int COUT, int KC, int coutr) {
        int tot = (kind == 0) ? 27 * KC * (COUT >> 4) * 512
                 : (kind == 1) ? 8 * 8 * KC * 512 : Cin * COUT * 64;
        tab.t[ti] = WTask{s, d, kind, Cin, COUT, KC, coutr, nb};
        nb += DIVUP(tot, 256); ti++;
    };
    addw(W1aa, wp1aa, 0, 16, 16, 1, 16);
    addw(W1b,  wp1b,  0, 16, 16, 1, 16);
    addw(W2a,  wp2a,  0, 16, 32, 1, 32);
    addw(W2aa, wp2aa, 0, 32, 32, 1, 32);
    addw(W2b,  wp2b,  0, 32, 32, 1, 32);
    addw(W20,  wp20,  0, 125, 32, 4, 32);
    addw(W10,  wp10,  0, 147, 32, 5, 32);
    addw(W00,  wp00,  0, 196, 32, 7, 32);
    addw(Wpf2, wpf2,  0, 32, 16, 1, 3);
    addw(Wpf1, wpf1,  0, 32, 16, 1, 3);
    addw(Wpf0, wpf0,  0, 32, 16, 1, 3);
    addw(Wuf1, wpd_uf1, 1, 32, 64, 4, 64);
    addw(Wuf2, wt_uf2, 2, 32, 3, 0, 3);
    addw(Wd2,  wt_d2,  2, 3, 3, 0, 3);
    addw(Wd1,  wt_d1,  2, 3, 3, 0, 3);
    addw(Wd0,  wt_d0,  2, 3, 3, 0, 3);
    tab.n = ti;
    wprep_k<<<nb, 256, 0, st>>>(tab);

    // ---- stage A (batched: b0=target->im1, b1=atlas->im2) ----
    conv3x3_k<4, 2><<<dim3(8, 8, 32), 256, 0, st>>>(target, atlas, W_ct, b_ct, im12,
                                                    SP(ST_IM), 1, 128, 128, 128,
                                                    16, (long)(4 * S64), 4);
    apply(st, im12, 8, S64, SP(ST_IM), nullptr, 0, 4, 0, im1clf, 4, 4);

    // ---- stage B (batched) ----
    // W1a: Cin=4 real channels -> fp32 direct conv from im12 (CP=32 bf16 path was
    // 8x byte-padded and 87%-zero MFMA K). Reads im12 fp32 (normalized in-place).
    conv3x3_k<16, 2><<<dim3(4, 4, 16), 256, 0, st>>>(im1, im2, W1a, b1a, A1,
                                                     SP(ST_A1), 4, 64, 64, 64,
                                                     8, (long)(16 * S32), 16);
    apply(st, A1, 32, S32, SP(ST_A1), A1cl, 32, 16, (long)(S32 * 32));
    mconv_k<32, 1, 1, 2, 16><<<dim3(4, 4, 32), 128, 0, st>>>(A1cl, wp1aa, b1aa, B1, SP(ST_B1),
        zbuf, 32, 32, 32, 16, (long)(S32 * 32), (long)(16 * S32), 16);
    apply(st, B1, 32, S32, SP(ST_B1), B1cl, 32, 16, (long)(S32 * 32));
    mconv_k<32, 1, 1, 2, 16><<<dim3(4, 4, 32), 128, 0, st>>>(B1cl, wp1b, b1b, c1121, SP(ST_C1),
        zbuf, 32, 32, 32, 16, (long)(S32 * 32), (long)(16 * S32), 16);
    apply(st, c1121, 32, S32, SP(ST_C1), c1121cl, 32, 16, (long)(S32 * 32), c11clf, 16, 16);

    // ---- stage C (batched) ----
    mconv_k<32, 2, 2, 4, 32><<<dim3(4, 4, 8), 256, 0, st>>>(c1121cl, wp2a, b2a, A2, SP(ST_A2),
        zbuf, 32, 32, 32, 4, (long)(S32 * 32), (long)(32 * S16), 32);
    apply(st, A2, 64, S16, SP(ST_A2), A2cl, 32, 32, (long)(S16 * 32));
    mconv_k<32, 2, 1, 2, 32><<<dim3(2, 2, 16), 128, 0, st>>>(A2cl, wp2aa, b2aa, B2, SP(ST_B2),
        zbuf, 16, 16, 16, 8, (long)(S16 * 32), (long)(32 * S16), 32);
    apply(st, B2, 64, S16, SP(ST_B2), B2cl, 32, 32, (long)(S16 * 32));
    mconv_k<32, 2, 1, 2, 32><<<dim3(2, 2, 16), 128, 0, st>>>(B2cl, wp2b, b2b, c12o, SP(ST_C2),
        zbuf, 16, 16, 16, 8, (long)(S16 * 32), (long)(c22o - c12o), 32);
    apply(st, c12o, 32, S16, SP(ST_C2), nullptr, 0, 32, 0);
    apply(st, c22o, 32, S16, SP(ST_C2 + 32), nullptr, 0, 32, 0);

    costvolw_k<32, 128, 0><<<DIVUP(S16, 4), 256, 0, st>>>(c12o, c22o, cv2cl, 16, 16, 16);
    mconv_k<128, 2, 1, 2, 32><<<dim3(2, 2, 8), 128, 0, st>>>(cv2cl, wp20, b20, x20, SP(ST_X20),
        zbuf, 16, 16, 16, 8, 0, 0, 0);
    apply(st, x20, 32, S16, SP(ST_X20), x20cl, 32, 32, 0);
    mconv_k<32, 1, 1, 2, 3><<<dim3(2, 2, 8), 128, 0, st>>>(x20cl, wpf2, bpf2, flow2, nullptr,
        zbuf, 16, 16, 16, 8, 0, 0, 0);
    dctn_k<3><<<DIVUP(8 * S16, 256), 256, 0, st>>>(flow2, wt_d2, bd2, upflow2, x147cl, 141, 160, 16);
    dctn_k<32><<<DIVUP(8 * S16, 256), 256, 0, st>>>(x20, wt_uf2, buf2, nullptr, x147cl, 144, 160, 16);

    // ---- stage D ----
    warpcl_k<16><<<DIVUP(S32, 256), 256, 0, st>>>(c21, upflow2, warp1clf, 32, 32, 32);
    costvolcl_k<16, 160, 2><<<(unsigned)(S32 / 8), 256, 0, st>>>(c11clf, warp1clf, x147cl,
                                                                 32, 32, 32);
    mconv_k<160, 2, 1, 2, 32><<<dim3(4, 4, 16), 128, 0, st>>>(x147cl, wp10, b10, x10, SP(ST_X10),
        zbuf, 32, 32, 32, 16, 0, 0, 0);
    apply(st, x10, 32, S32, SP(ST_X10), x10cl, 32, 32, 0);
    mconv_k<32, 1, 1, 2, 3><<<dim3(4, 4, 16), 128, 0, st>>>(x10cl, wpf1, bpf1, flow1, nullptr,
        zbuf, 32, 32, 32, 16, 0, 0, 0);
    dctn_k<3><<<DIVUP(8 * S32, 256), 256, 0, st>>>(flow1, wt_d1, bd1, upflow1, x196cl, 129, 224, 32);
    mdeconv_k<4><<<dim3(4, 4, 64), 256, 0, st>>>(x10cl, wpd_uf1, buf1, x196cl, 132, 224, 32);

    // ---- stage E ----
    warpcl_k<4><<<DIVUP(S64, 256), 256, 0, st>>>(im2, upflow1, warp0clf, 64, 64, 64);
    costvolcl_k<4, 224, 4><<<(unsigned)(S64 / 16), 256, 0, st>>>(im1clf, warp0clf, x196cl,
                                                                 64, 64, 64);
    mconv_k<224, 2, 1, 4, 32><<<dim3(8, 8, 16), 256, 0, st>>>(x196cl, wp00, b00, x00, SP(ST_X00),
        zbuf, 64, 64, 64, 16, 0, 0, 0);
    apply(st, x00, 32, S64, SP(ST_X00), x00cl, 32, 32, 0);
    mconv_k<32, 1, 1, 4, 3><<<dim3(8, 8, 16), 256, 0, st>>>(x00cl, wpf0, bpf0, flow0, nullptr,
        zbuf, 64, 64, 64, 16, 0, 0, 0);
    dctn_k<3><<<DIVUP(S128, 256), 256, 0, st>>>(flow0, wt_d0, bd0, outF, nullptr, 0, 0, 64);
}

// Round 10
// 859.332 us; speedup vs baseline: 1.2210x; 1.2210x over previous
//
#include <hip/hip_runtime.h>
#include <cstddef>
#include <cstdint>

#define DIVUP(a,b) (((a)+(b)-1)/(b))

typedef __attribute__((ext_vector_type(8))) short short8;
typedef __attribute__((ext_vector_type(4))) float f32x4;

__device__ __forceinline__ ushort f2bf(float f) {
    union { float f; uint32_t u; } v; v.f = f;
    uint32_t r = v.u + 0x7fffu + ((v.u >> 16) & 1u);
    return (ushort)(r >> 16);
}

// XCD-chunked block swizzle (kept; neutral on FETCH, cheap).
struct SwzB { int x, y, z; };
__device__ __forceinline__ SwzB swz_block() {
    int gx = gridDim.x, gy = gridDim.y;
    int n = gx * gy * gridDim.z;
    int lin = blockIdx.x + gx * (blockIdx.y + gy * blockIdx.z);
    if ((n & 7) == 0)
        lin = (lin & 7) * (n >> 3) + (lin >> 3);
    SwzB s;
    s.x = lin % gx;
    int t = lin / gx;
    s.y = t % gy;
    s.z = t / gy;
    return s;
}

// ============ fp32 direct conv (small-Cin stride-2 convs: W_ct, W1a), batched ======
template<int COUT, int STRIDE>
__global__ __launch_bounds__(256)
void conv3x3_k(const float* __restrict__ in0, const float* __restrict__ in1,
               const float* __restrict__ wgt, const float* __restrict__ bias,
               float* __restrict__ out, float* __restrict__ stats,
               int Cin, int D, int H, int W, int nz, long out_bs, int st_bs)
{
    constexpr int TD = 4, TH = 8, TW = 8;
    constexpr int ID = 2 * TD + 1, IH = 2 * TH + 1, IW = 2 * TW + 1;
    __shared__ float tile[ID * IH * IW];
    const int b = blockIdx.z / nz, zb = blockIdx.z % nz;
    const float* in = b ? in1 : in0;
    out += (long)b * out_bs;
    if (stats) stats += 2 * st_bs * b;
    const int Do = D / STRIDE, Ho = H / STRIDE, Wo = W / STRIDE;
    const int tid = threadIdx.x;
    const int tw = tid & 7, th = (tid >> 3) & 7, td = tid >> 6;
    const int ow0 = blockIdx.x * TW, oh0 = blockIdx.y * TH, od0 = zb * TD;
    const int iw0 = ow0 * STRIDE - 1, ih0 = oh0 * STRIDE - 1, id0 = od0 * STRIDE - 1;
    const size_t HWs = (size_t)H * W;

    float acc[COUT];
#pragma unroll
    for (int i = 0; i < COUT; i++) acc[i] = 0.f;

    for (int c = 0; c < Cin; ++c) {
        const float* inc = in + (size_t)c * D * HWs;
        for (int i = tid; i < ID * IH * IW; i += 256) {
            int lw = i % IW, lh = (i / IW) % IH, ld = i / (IW * IH);
            int gw = iw0 + lw, gh = ih0 + lh, gd = id0 + ld;
            float v = 0.f;
            if ((unsigned)gw < (unsigned)W && (unsigned)gh < (unsigned)H &&
                (unsigned)gd < (unsigned)D)
                v = inc[(size_t)gd * HWs + (size_t)gh * W + gw];
            tile[i] = v;
        }
        __syncthreads();
        float r[27];
        const int bd = td * STRIDE, bh = th * STRIDE, bw = tw * STRIDE;
#pragma unroll
        for (int kd = 0; kd < 3; kd++)
#pragma unroll
            for (int kh = 0; kh < 3; kh++)
#pragma unroll
                for (int kw = 0; kw < 3; kw++)
                    r[kd * 9 + kh * 3 + kw] =
                        tile[(bd + kd) * (IH * IW) + (bh + kh) * IW + (bw + kw)];
#pragma unroll
        for (int oc = 0; oc < COUT; ++oc) {
            const float* wp = wgt + ((size_t)oc * Cin + c) * 27;
            float s = 0.f;
#pragma unroll
            for (int t = 0; t < 27; t++) s = fmaf(wp[t], r[t], s);
            acc[oc] += s;
        }
        __syncthreads();
    }
    const size_t So = (size_t)Do * Ho * Wo;
    const size_t sp = (size_t)(od0 + td) * Ho * Wo + (size_t)(oh0 + th) * Wo + (ow0 + tw);
#pragma unroll
    for (int oc = 0; oc < COUT; ++oc)
        out[(size_t)oc * So + sp] = acc[oc] + bias[oc];

    if (stats) {
        __syncthreads();
        float* sm = tile;
        const int wv = tid >> 6, l = tid & 63;
#pragma unroll
        for (int oc = 0; oc < COUT; ++oc) {
            float sv = acc[oc] + bias[oc];
            float sq = sv * sv;
#pragma unroll
            for (int o = 32; o > 0; o >>= 1) {
                sv += __shfl_down(sv, o, 64);
                sq += __shfl_down(sq, o, 64);
            }
            if (l == 0) { sm[(wv * COUT + oc) * 2] = sv; sm[(wv * COUT + oc) * 2 + 1] = sq; }
        }
        __syncthreads();
        if (tid < COUT) {
            float s = 0.f, s2 = 0.f;
#pragma unroll
            for (int w = 0; w < 4; ++w) {
                s += sm[(w * COUT + tid) * 2];
                s2 += sm[(w * COUT + tid) * 2 + 1];
            }
            atomicAdd(&stats[2 * tid], s);
            atomicAdd(&stats[2 * tid + 1], s2);
        }
    }
}

// ============ MFMA implicit-GEMM conv (fused stats, batched) =================
// Weight layout (wprep kind 0): [kc][kd][kh][kw][nf][512].
// STRIDE==1: per-kd weight slices double-buffered in LDS via global_load_lds
// issued before the compute phase using the other buffer -> compute VMEM-free.
// Halo stays on the plain gll path: round-9 showed reg-prefetching it through
// ds_write adds LDS-port traffic to an LDS-bound kernel (125->144us). Round-7
// showed weight-LDS staging only pays where bf loads vmcnt-couple with async
// halo staging (stride-1 family); STRIDE==2 keeps per-wave L2 weight loads.
template<int CP, int NF, int STRIDE, int MW, int COUTR>
__global__ __launch_bounds__(MW * 64, (STRIDE == 1) ? 2 : 4)
void mconv_k(const ushort* __restrict__ xcl, const ushort* __restrict__ wp,
             const float* __restrict__ bias, float* __restrict__ outcf,
             float* __restrict__ stats, const ushort* __restrict__ zbuf,
             int D, int H, int W, int nz, long in_bs, long out_bs, int st_bs)
{
    constexpr int KC = CP / 32;
    constexpr int MF = (STRIDE == 1) ? 4 : 1;
    constexpr int TD = MW;
    constexpr int TWl = (STRIDE == 1) ? 8 : 4;
    constexpr int HD = (STRIDE == 1) ? TD + 2 : 2 * TD + 1;
    constexpr int HH = (STRIDE == 1) ? 10 : 9;
    constexpr int HWd = (STRIDE == 1) ? 10 : 9;
    constexpr int HALO = HD * HH * HWd;
    constexpr int NTH = MW * 64;
    constexpr int NIT = (HALO * 4 + NTH - 1) / NTH;
    constexpr int PITCH = (STRIDE == 1) ? 32 : 40;   // ushorts per point
    constexpr int LDSZ_H = (STRIDE == 1) ? NIT * NTH * 8 : HALO * 40;
    constexpr int NITW = (9 * NF * 512 + NTH * 8 - 1) / (NTH * 8);    // per-kd (s1)
    constexpr int LDSZ_W = NITW * NTH * 8;
    constexpr int LDS_TOT = (STRIDE == 1) ? LDSZ_H + 2 * LDSZ_W : LDSZ_H;
    __shared__ __align__(16) ushort lds[LDS_TOT];

    const int tid = threadIdx.x;
    const int wv = tid >> 6, l = tid & 63;
    const SwzB sb = swz_block();
    const int b = sb.z / nz, zb = sb.z % nz;
    xcl += (long)b * in_bs;
    outcf += (long)b * out_bs;
    if (stats) stats += 2 * st_bs * b;
    const int od0 = zb * TD, oh0 = sb.y * ((STRIDE == 1) ? 8 : 4),
              ow0 = sb.x * TWl;
    const int id0 = od0 * STRIDE - 1, ih0 = oh0 * STRIDE - 1, iw0 = ow0 * STRIDE - 1;

    f32x4 acc[MF][NF];
#pragma unroll
    for (int mf = 0; mf < MF; mf++)
#pragma unroll
        for (int nf = 0; nf < NF; nf++) acc[mf][nf] = f32x4{0.f, 0.f, 0.f, 0.f};

    auto woff = [&](int kc, int kd, int kh, int kw, int nf) -> size_t {
        return ((((size_t)(kc * 3 + kd) * 3 + kh) * 3 + kw) * NF + nf) << 9;
    };

    if constexpr (STRIDE == 1) {
        ushort* const hab = lds;
        ushort* const wbA = lds + LDSZ_H;
        ushort* const wbB = lds + LDSZ_H + LDSZ_W;

        auto hstage = [&](int kc) {
#pragma unroll
            for (int it = 0; it < NIT; ++it) {
                int idx = it * NTH + tid;
                int pt = idx >> 2, part = idx & 3;
                int lw = pt % HWd, lh = (pt / HWd) % HH, ld = pt / (HWd * HH);
                int gx = iw0 + lw, gy = ih0 + lh, gz = id0 + ld;
                const ushort* src = zbuf;
                if (pt < HALO && (unsigned)gx < (unsigned)W &&
                    (unsigned)gy < (unsigned)H && (unsigned)gz < (unsigned)D)
                    src = xcl + (size_t)((gz * H + gy) * W + gx) * CP + part * 8;
                __builtin_amdgcn_global_load_lds(
                    (const __attribute__((address_space(1))) uint32_t*)(src + kc * 32),
                    (__attribute__((address_space(3))) uint32_t*)
                        &hab[(size_t)(it * NTH + (wv << 6)) * 8],
                    16, 0, 0);
            }
        };
        auto wstage = [&](int kc, int kd, ushort* dst) {
#pragma unroll
            for (int it = 0; it < NITW; ++it) {
                int idx = it * NTH + tid;
                const ushort* src = (idx < 9 * NF * 64)
                    ? wp + ((size_t)(kc * 3 + kd) * 9 * NF * 512 + (size_t)idx * 8)
                    : zbuf;
                __builtin_amdgcn_global_load_lds(
                    (const __attribute__((address_space(1))) uint32_t*)src,
                    (__attribute__((address_space(3))) uint32_t*)
                        &dst[(size_t)(it * NTH + (wv << 6)) * 8],
                    16, 0, 0);
            }
        };
        auto compute = [&](int kd, const ushort* w) {
#pragma unroll
            for (int kw = 0; kw < 3; ++kw) {
                short8 af[9];
#pragma unroll
                for (int r = 0; r < 9; ++r)
                    af[r] = *reinterpret_cast<const short8*>(
                        &hab[((wv + kd) * (HH * HWd) +
                              (r + ((l >> 3) & 1)) * HWd + (l & 7) + kw) * PITCH +
                             ((l >> 4) << 3)]);
#pragma unroll
                for (int kh = 0; kh < 3; ++kh) {
                    short8 bf[NF];
#pragma unroll
                    for (int nf = 0; nf < NF; ++nf)
                        bf[nf] = *reinterpret_cast<const short8*>(
                            &w[(size_t)(((kh * 3 + kw) * NF) + nf) * 512 + (l << 3)]);
#pragma unroll
                    for (int mf = 0; mf < MF; ++mf)
#pragma unroll
                        for (int nf = 0; nf < NF; ++nf)
                            acc[mf][nf] = __builtin_amdgcn_mfma_f32_16x16x32_bf16(
                                af[2 * mf + kh], bf[nf], acc[mf][nf], 0, 0, 0);
                }
            }
        };

        for (int kc = 0; kc < KC; ++kc) {
            hstage(kc);
            wstage(kc, 0, wbA);
            __syncthreads();         // drain vmcnt(0): halo + w0 landed
            wstage(kc, 1, wbB);
            compute(0, wbA);
            __syncthreads();         // w1 landed; done reading wbA
            wstage(kc, 2, wbA);
            compute(1, wbB);
            __syncthreads();         // w2 landed; done reading wbB
            compute(2, wbA);
            __syncthreads();         // done reading hab/wbA before next kc staging
        }
    } else {
        uint4 v[NIT];
        auto stage = [&](int kc) {
#pragma unroll
            for (int it = 0; it < NIT; ++it) {
                int idx = it * NTH + tid;
                uint4 t = {0u, 0u, 0u, 0u};
                if (idx < HALO * 4) {
                    int pt = idx >> 2, part = idx & 3;
                    int lw = pt % HWd, lh = (pt / HWd) % HH, ld = pt / (HWd * HH);
                    int gx = iw0 + lw, gy = ih0 + lh, gz = id0 + ld;
                    if ((unsigned)gx < (unsigned)W && (unsigned)gy < (unsigned)H &&
                        (unsigned)gz < (unsigned)D)
                        t = *reinterpret_cast<const uint4*>(
                            xcl + ((size_t)((gz * H + gy) * W + gx)) * CP + kc * 32 + part * 8);
                }
                v[it] = t;
            }
        };

        stage(0);
        for (int kc = 0; kc < KC; ++kc) {
            if (kc) __syncthreads();
#pragma unroll
            for (int it = 0; it < NIT; ++it) {
                int idx = it * NTH + tid;
                if (idx < HALO * 4)
                    *reinterpret_cast<uint4*>(&lds[(idx >> 2) * PITCH + (idx & 3) * 8]) = v[it];
            }
            __syncthreads();
            if (kc + 1 < KC) stage(kc + 1);
#pragma unroll
            for (int t = 0; t < 27; ++t) {
                const int kd = t / 9, kh = (t / 3) % 3, kw = t % 3;
                short8 bf[NF];
#pragma unroll
                for (int nf = 0; nf < NF; ++nf)
                    bf[nf] = *reinterpret_cast<const short8*>(
                        wp + woff(kc, kd, kh, kw, nf) + (l << 3));
                int bw = l & 3, bh = (l >> 2) & 3;
                int p_loc = (2 * wv + kd) * (HH * HWd) + (2 * bh + kh) * HWd + (2 * bw + kw);
                short8 afs = *reinterpret_cast<const short8*>(&lds[p_loc * PITCH + ((l >> 4) << 3)]);
#pragma unroll
                for (int nf = 0; nf < NF; ++nf)
                    acc[0][nf] = __builtin_amdgcn_mfma_f32_16x16x32_bf16(
                        afs, bf[nf], acc[0][nf], 0, 0, 0);
            }
        }
    }
    const int Do = D / STRIDE, Ho = H / STRIDE, Wo = W / STRIDE;
    const size_t So = (size_t)Do * Ho * Wo;
    float ps[NF], ps2[NF];
#pragma unroll
    for (int nf = 0; nf < NF; ++nf) { ps[nf] = 0.f; ps2[nf] = 0.f; }
#pragma unroll
    for (int nf = 0; nf < NF; ++nf) {
        int oc = nf * 16 + (l & 15);
        float bv = (oc < COUTR) ? bias[oc] : 0.f;
#pragma unroll
        for (int mf = 0; mf < MF; ++mf) {
#pragma unroll
            for (int r = 0; r < 4; ++r) {
                int q = ((l >> 4) << 2) + r;
                int bw, bh;
                if (STRIDE == 1) { bw = q & 7; bh = 2 * mf + (q >> 3); }
                else             { bw = q & 3; bh = (q >> 2) & 3; }
                int p = ((od0 + wv) * Ho + (oh0 + bh)) * Wo + (ow0 + bw);
                float val = acc[mf][nf][r] + bv;
                if (oc < COUTR) {
                    outcf[(size_t)oc * So + p] = val;
                    ps[nf] += val; ps2[nf] = fmaf(val, val, ps2[nf]);
                }
            }
        }
    }
    if (stats) {
        __syncthreads();
        float* sm = (float*)lds;
#pragma unroll
        for (int nf = 0; nf < NF; ++nf) {
            float s = ps[nf], s2 = ps2[nf];
            s += __shfl_down(s, 32, 64);  s2 += __shfl_down(s2, 32, 64);
            s += __shfl_down(s, 16, 64);  s2 += __shfl_down(s2, 16, 64);
            if (l < 16) {
                sm[((wv * NF + nf) * 16 + l) * 2] = s;
                sm[((wv * NF + nf) * 16 + l) * 2 + 1] = s2;
            }
        }
        __syncthreads();
        if (tid < NF * 16) {
            int nf = tid >> 4, c = tid & 15, oc = nf * 16 + c;
            if (oc < COUTR) {
                float s = 0.f, s2 = 0.f;
#pragma unroll
                for (int w = 0; w < MW; ++w) {
                    s += sm[((w * NF + nf) * 16 + c) * 2];
                    s2 += sm[((w * NF + nf) * 16 + c) * 2 + 1];
                }
                atomicAdd(&stats[2 * oc], s);
                atomicAdd(&stats[2 * oc + 1], s2);
            }
        }
    }
}

// ======================= consolidated weight prep ============================
struct WTask { const float* src; void* dst; int kind, Cin, COUT, KC, coutr, base; };
struct WTab { WTask t[17]; int n; };

__global__ __launch_bounds__(256)
void wprep_k(WTab tab)
{
    int b = blockIdx.x, ti = 0;
    for (int i = 0; i < tab.n; ++i) if (b >= tab.t[i].base) ti = i;
    const WTask tk = tab.t[ti];
    int idx = (b - tk.base) * 256 + threadIdx.x;
    if (tk.kind == 0) {
        // layout: [kc][kd][kh][kw][nf][512]
        int NF = tk.COUT >> 4;
        int tot = 27 * tk.KC * NF * 512;
        if (idx >= tot) return;
        int j = idx & 7, l = (idx >> 3) & 63;
        int g = idx >> 9;
        int nf = g % NF; g /= NF;
        int kw = g % 3; g /= 3;
        int kh = g % 3; g /= 3;
        int kd = g % 3; int kc = g / 3;
        int t = kd * 9 + kh * 3 + kw;
        int oc = nf * 16 + (l & 15);
        int c = kc * 32 + ((l >> 4) << 3) + j;
        float v = (c < tk.Cin && oc < tk.coutr)
                      ? tk.src[((size_t)oc * tk.Cin + c) * 27 + t] : 0.f;
        ((ushort*)tk.dst)[idx] = f2bf(v);
    } else if (tk.kind == 1) {
        int NF = tk.KC;
        int tot = 8 * 8 * NF * 512;
        if (idx >= tot) return;
        int j = idx & 7, l = (idx >> 3) & 63;
        int g = idx >> 9;
        int nf = g % NF; g /= NF;
        int t = g % 8; int pp = g / 8;
        int oc = nf * 16 + (l & 15);
        int c = ((l >> 4) << 3) + j;
        int kd_ = (t >> 2) & 1, kh_ = (t >> 1) & 1, kw_ = t & 1;
        int pd = (pp >> 2) & 1, ph = (pp >> 1) & 1, pw = pp & 1;
        int kd = 3 - pd - 2 * kd_, kh = 3 - ph - 2 * kh_, kw = 3 - pw - 2 * kw_;
        float v = (oc < tk.COUT)
                      ? tk.src[(size_t)(c * tk.COUT + oc) * 64 + kd * 16 + kh * 4 + kw] : 0.f;
        ((ushort*)tk.dst)[idx] = f2bf(v);
    } else {
        int tot = tk.Cin * tk.COUT * 64;
        if (idx >= tot) return;
        int k = idx & 63; int oc = (idx >> 6) % tk.COUT; int c = (idx >> 6) / tk.COUT;
        ((float*)tk.dst)[((size_t)c * 64 + k) * tk.COUT + oc] = tk.src[idx];
    }
}

// ======================= MFMA deconv (uf1) =======================
template<int NF>
__global__ __launch_bounds__(256)
void mdeconv_k(const ushort* __restrict__ xcl, const ushort* __restrict__ wpd,
               const float* __restrict__ bias, ushort* __restrict__ outcl,
               int c0, int CPo, int Si)
{
    constexpr int HD = 5, HH = 9, HWd = 9, HALO = HD * HH * HWd;
    constexpr int PITCH = 32;
    __shared__ __align__(16) ushort lds[HALO * PITCH];
    const int tid = threadIdx.x, wv = tid >> 6, l = tid & 63;
    const SwzB sb = swz_block();
    const int pp = sb.z & 7, tz = sb.z >> 3;
    const int pd = (pp >> 2) & 1, ph = (pp >> 1) & 1, pw = pp & 1;
    const int oz0 = tz * 4, oy0 = sb.y * 8, ox0 = sb.x * 8;
    const int iz0 = oz0 + pd - 1, iy0 = oy0 + ph - 1, ix0 = ox0 + pw - 1;

    for (int idx = tid; idx < HALO * 4; idx += 256) {
        int pt = idx >> 2, part = idx & 3;
        int lw = pt % HWd, lh = (pt / HWd) % HH, ld = pt / (HWd * HH);
        int gx = ix0 + lw, gy = iy0 + lh, gz = iz0 + ld;
        uint4 t = {0u, 0u, 0u, 0u};
        if ((unsigned)gx < (unsigned)Si && (unsigned)gy < (unsigned)Si &&
            (unsigned)gz < (unsigned)Si)
            t = *reinterpret_cast<const uint4*>(
                xcl + ((size_t)((gz * Si + gy) * Si + gx)) * 32 + part * 8);
        *reinterpret_cast<uint4*>(&lds[pt * PITCH + part * 8]) = t;
    }
    __syncthreads();

    f32x4 acc[4][NF];
#pragma unroll
    for (int mf = 0; mf < 4; mf++)
#pragma unroll
        for (int nf = 0; nf < NF; nf++) acc[mf][nf] = f32x4{0.f, 0.f, 0.f, 0.f};

#pragma unroll
    for (int kd = 0; kd < 2; ++kd) {
#pragma unroll
        for (int kw = 0; kw < 2; ++kw) {
            short8 af[8];
#pragma unroll
            for (int r = 0; r < 8; ++r)
                af[r] = *reinterpret_cast<const short8*>(
                    &lds[((wv + kd) * (HH * HWd) + (r + ((l >> 3) & 1)) * HWd +
                          (l & 7) + kw) * PITCH + ((l >> 4) << 3)]);
#pragma unroll
            for (int kh = 0; kh < 2; ++kh) {
                const int t = kd * 4 + kh * 2 + kw;
                short8 bf[NF];
#pragma unroll
                for (int nf = 0; nf < NF; ++nf)
                    bf[nf] = *reinterpret_cast<const short8*>(
                        wpd + (((size_t)(pp * 8 + t) * NF + nf) << 9) + (l << 3));
#pragma unroll
                for (int mf = 0; mf < 4; ++mf)
#pragma unroll
                    for (int nf = 0; nf < NF; ++nf)
                        acc[mf][nf] = __builtin_amdgcn_mfma_f32_16x16x32_bf16(
                            af[2 * mf + kh], bf[nf], acc[mf][nf], 0, 0, 0);
            }
        }
    }
    const int Do = 2 * Si;
#pragma unroll
    for (int nf = 0; nf < NF; ++nf) {
        int oc = nf * 16 + (l & 15);
        float bv = bias[oc];
#pragma unroll
        for (int mf = 0; mf < 4; ++mf) {
#pragma unroll
            for (int r = 0; r < 4; ++r) {
                int q = ((l >> 4) << 2) + r;
                int bw = q & 7, bh = 2 * mf + (q >> 3);
                int oD = 2 * (oz0 + wv) + pd, oH = 2 * (oy0 + bh) + ph, oW = 2 * (ox0 + bw) + pw;
                outcl[(size_t)((oD * Do + oH) * Do + oW) * CPo + c0 + oc] =
                    f2bf(acc[mf][nf][r] + bv);
            }
        }
    }
}

// ======================= output-centric small deconv (COUT=3) ====
template<int CIN>
__global__ __launch_bounds__(256)
void dctn_k(const float* __restrict__ in, const float* __restrict__ wt,
            const float* __restrict__ bias, float* __restrict__ outcf,
            ushort* __restrict__ outcl, int c0, int CPo, int Si)
{
    const int Do = 2 * Si;
    const size_t So = (size_t)Do * Do * Do, ni = (size_t)Si * Si * Si;
    size_t p = (size_t)blockIdx.x * 256 + threadIdx.x;
    if (p >= So) return;
    int oxW = (int)(p % Do), oyH = (int)((p / Do) % Do), ozD = (int)(p / ((size_t)Do * Do));
    int pw = oxW & 1, ph = oyH & 1, pd = ozD & 1;
    int xb = oxW >> 1, yb = oyH >> 1, zb = ozD >> 1;
    float acc[3] = {0.f, 0.f, 0.f};
    for (int c = 0; c < CIN; ++c) {
        const float* inc = in + (size_t)c * ni;
        const float* wc = wt + (size_t)c * 64 * 3;
#pragma unroll
        for (int jd = 0; jd < 2; jd++) {
            int iz = zb + pd - jd; if ((unsigned)iz >= (unsigned)Si) continue;
            int kd = 1 - pd + 2 * jd;
#pragma unroll
            for (int jh = 0; jh < 2; jh++) {
                int iy = yb + ph - jh; if ((unsigned)iy >= (unsigned)Si) continue;
                int kh = 1 - ph + 2 * jh;
#pragma unroll
                for (int jw = 0; jw < 2; jw++) {
                    int ix = xb + pw - jw; if ((unsigned)ix >= (unsigned)Si) continue;
                    int kw = 1 - pw + 2 * jw;
                    float v = inc[((size_t)iz * Si + iy) * Si + ix];
                    const float* wr = wc + (size_t)((kd * 4 + kh) * 4 + kw) * 3;
                    acc[0] = fmaf(wr[0], v, acc[0]);
                    acc[1] = fmaf(wr[1], v, acc[1]);
                    acc[2] = fmaf(wr[2], v, acc[2]);
                }
            }
        }
    }
#pragma unroll
    for (int oc = 0; oc < 3; ++oc) {
        float o = acc[oc] + bias[oc];
        if (outcf) outcf[(size_t)oc * So + p] = o;
        if (outcl) outcl[p * CPo + c0 + oc] = f2bf(o);
    }
}

// ============ instance norm apply (batched ycl via Cper; optional ch-last f32) =====
__global__ __launch_bounds__(256)
void inorm_apply_k(const float* __restrict__ x, const float* __restrict__ stats,
                   float* __restrict__ y, size_t S, float invS,
                   ushort* __restrict__ ycl, int CP, int Cper, long ycl_bs,
                   float* __restrict__ yclf, int CPf, int Cf)
{
    int c = blockIdx.y;
    float sum = stats[2 * c], ss = stats[2 * c + 1];
    float m = sum * invS;
    float r = rsqrtf(fmaxf(ss * invS - m * m, 0.f) + 1e-5f);
    size_t i = (size_t)blockIdx.x * 256 + threadIdx.x;
    if (i >= S) return;
    float v = (x[(size_t)c * S + i] - m) * r;
    v = v >= 0.f ? v : 0.1f * v;
    y[(size_t)c * S + i] = v;
    if (ycl) {
        int b = c / Cper, cl = c - b * Cper;
        ycl[(long)b * ycl_bs + (long)i * CP + cl] = f2bf(v);
    }
    if (yclf && c < Cf)
        yclf[i * (size_t)CPf + c] = v;
}

// ======================= cost volume (ch-major, stage-2 only) =========
template<int C, int CP, int COPYC>
__global__ __launch_bounds__(256)
void costvolw_k(const float* __restrict__ f1, const float* __restrict__ f2,
                ushort* __restrict__ outcl, int D, int H, int W)
{
    const size_t S = (size_t)D * H * W;
    size_t p = (size_t)blockIdx.x * 4 + (threadIdx.x >> 6);
    if (p >= S) return;
    const int l = threadIdx.x & 63;
    int x = (int)(p % W); int y = (int)((p / W) % H); int z = (int)(p / ((size_t)W * H));
    float a[C];
#pragma unroll
    for (int c = 0; c < C; c++) a[c] = f1[(size_t)c * S + p];
    const float inv = 1.f / C;
    ushort* op = outcl + p * CP;
#pragma unroll
    for (int rep = 0; rep < 2; rep++) {
        int s = l + rep * 64;
        if (s < 125) {
            int v = s / 25 - 2, h = (s / 5) % 5 - 2, d = s % 5 - 2;
            int zz = z + v, yy = y + h, xx = x + d;
            float acc = 0.f;
            if ((unsigned)zz < (unsigned)D && (unsigned)yy < (unsigned)H &&
                (unsigned)xx < (unsigned)W) {
                size_t q = ((size_t)zz * H + yy) * (size_t)W + xx;
#pragma unroll
                for (int c = 0; c < C; c++) acc = fmaf(a[c], f2[(size_t)c * S + q], acc);
            }
            acc *= inv;
            op[s] = f2bf(acc >= 0.f ? acc : 0.1f * acc);
        }
    }
    if (COPYC && l < C)
        op[125 + l] = f2bf(f1[(size_t)l * S + p]);
}

// ============ cost volume, channel-last fp32 operands, NP points/wave ============
template<int C, int CP, int NP>
__global__ __launch_bounds__(256)
void costvolcl_k(const float* __restrict__ f1cl, const float* __restrict__ f2cl,
                 ushort* __restrict__ outcl, int D, int H, int W)
{
    const size_t S = (size_t)D * H * W;
    size_t p0 = ((size_t)blockIdx.x * 4 + (threadIdx.x >> 6)) * NP;
    if (p0 >= S) return;
    const int l = threadIdx.x & 63;
    float a[NP][C];
#pragma unroll
    for (int pp = 0; pp < NP; pp++)
#pragma unroll
        for (int c4 = 0; c4 < C / 4; c4++) {
            float4 t = *reinterpret_cast<const float4*>(&f1cl[(p0 + pp) * C + c4 * 4]);
            a[pp][c4 * 4 + 0] = t.x; a[pp][c4 * 4 + 1] = t.y;
            a[pp][c4 * 4 + 2] = t.z; a[pp][c4 * 4 + 3] = t.w;
        }
    const float inv = 1.f / C;
#pragma unroll
    for (int rep = 0; rep < 2; rep++) {
        int s = l + rep * 64;
        int v = s / 25 - 2, h = (s / 5) % 5 - 2, d = s % 5 - 2;
        bool sv = s < 125;
#pragma unroll
        for (int pp = 0; pp < NP; pp++) {
            size_t p = p0 + pp;
            int x = (int)(p % W), y = (int)((p / W) % H), z = (int)(p / ((size_t)W * H));
            int zz = z + v, yy = y + h, xx = x + d;
            float acc = 0.f;
            if (sv && (unsigned)zz < (unsigned)D && (unsigned)yy < (unsigned)H &&
                (unsigned)xx < (unsigned)W) {
                size_t q = ((size_t)zz * H + yy) * (size_t)W + xx;
#pragma unroll
                for (int c4 = 0; c4 < C / 4; c4++) {
                    float4 b = *reinterpret_cast<const float4*>(&f2cl[q * C + c4 * 4]);
                    acc = fmaf(a[pp][c4 * 4 + 0], b.x, acc);
                    acc = fmaf(a[pp][c4 * 4 + 1], b.y, acc);
                    acc = fmaf(a[pp][c4 * 4 + 2], b.z, acc);
                    acc = fmaf(a[pp][c4 * 4 + 3], b.w, acc);
                }
            }
            if (sv) {
                acc *= inv;
                outcl[p * CP + s] = f2bf(acc >= 0.f ? acc : 0.1f * acc);
            }
        }
    }
    if (l < C) {
#pragma unroll
        for (int pp = 0; pp < NP; pp++)
            outcl[(p0 + pp) * CP + 125 + l] = f2bf(f1cl[(p0 + pp) * C + l]);
    }
}

// ======================= trilinear warp (clamped), channel-last out ===========
template<int C>
__global__ __launch_bounds__(256)
void warpcl_k(const float* __restrict__ img, const float* __restrict__ flow,
              float* __restrict__ outcl, int D, int H, int W)
{
    const size_t S = (size_t)D * H * W;
    size_t p = (size_t)blockIdx.x * 256 + threadIdx.x;
    if (p >= S) return;
    int x = (int)(p % W); int y = (int)((p / W) % H); int z = (int)(p / ((size_t)W * H));
    float cd = fminf(fmaxf((float)z + flow[p], 0.f), (float)(D - 1));
    float ch = fminf(fmaxf((float)y + flow[S + p], 0.f), (float)(H - 1));
    float cw = fminf(fmaxf((float)x + flow[2 * S + p], 0.f), (float)(W - 1));
    int d0 = (int)cd, h0 = (int)ch, w0 = (int)cw;
    float fd = cd - d0, fh = ch - h0, fw = cw - w0;
    int d1 = min(d0 + 1, D - 1), h1 = min(h0 + 1, H - 1), w1 = min(w0 + 1, W - 1);
    size_t i000 = ((size_t)d0 * H + h0) * W + w0, i001 = ((size_t)d0 * H + h0) * W + w1;
    size_t i010 = ((size_t)d0 * H + h1) * W + w0, i011 = ((size_t)d0 * H + h1) * W + w1;
    size_t i100 = ((size_t)d1 * H + h0) * W + w0, i101 = ((size_t)d1 * H + h0) * W + w1;
    size_t i110 = ((size_t)d1 * H + h1) * W + w0, i111 = ((size_t)d1 * H + h1) * W + w1;
    float w000 = (1 - fd) * (1 - fh) * (1 - fw), w001 = (1 - fd) * (1 - fh) * fw;
    float w010 = (1 - fd) * fh * (1 - fw),       w011 = (1 - fd) * fh * fw;
    float w100 = fd * (1 - fh) * (1 - fw),       w101 = fd * (1 - fh) * fw;
    float w110 = fd * fh * (1 - fw),             w111 = fd * fh * fw;
#pragma unroll
    for (int c4 = 0; c4 < C / 4; c4++) {
        float4 r;
        float* rr = reinterpret_cast<float*>(&r);
#pragma unroll
        for (int j = 0; j < 4; j++) {
            const float* ic = img + (size_t)(c4 * 4 + j) * S;
            rr[j] = w000 * ic[i000] + w001 * ic[i001] + w010 * ic[i010] + w011 * ic[i011]
                  + w100 * ic[i100] + w101 * ic[i101] + w110 * ic[i110] + w111 * ic[i111];
        }
        *reinterpret_cast<float4*>(&outcl[p * C + c4 * 4]) = r;
    }
}

// ======================= host orchestration =======================
static void apply(hipStream_t st, float* x, int C, size_t S, const float* stats,
                  ushort* ycl, int CP, int Cper, long ycl_bs,
                  float* yclf = nullptr, int CPf = 0, int Cf = 0)
{
    dim3 g((unsigned)DIVUP(S, 256), C);
    inorm_apply_k<<<g, 256, 0, st>>>(x, stats, x, S, 1.0f / (float)S, ycl, CP, Cper, ycl_bs,
                                     yclf, CPf, Cf);
}

extern "C" void kernel_launch(void* const* d_in, const int* in_sizes, int n_in,
                              void* d_out, int out_size, void* d_ws, size_t ws_size,
                              hipStream_t st)
{
    (void)in_sizes; (void)n_in; (void)out_size; (void)ws_size;
    const float* atlas  = (const float*)d_in[0];
    const float* target = (const float*)d_in[1];
    const float *W_ct = (const float*)d_in[2],  *b_ct = (const float*)d_in[3];
    const float *W1a  = (const float*)d_in[4],  *b1a  = (const float*)d_in[5];
    const float *W1aa = (const float*)d_in[6],  *b1aa = (const float*)d_in[7];
    const float *W1b  = (const float*)d_in[8],  *b1b  = (const float*)d_in[9];
    const float *W2a  = (const float*)d_in[10], *b2a  = (const float*)d_in[11];
    const float *W2aa = (const float*)d_in[12], *b2aa = (const float*)d_in[13];
    const float *W2b  = (const float*)d_in[14], *b2b  = (const float*)d_in[15];
    const float *W20  = (const float*)d_in[16], *b20  = (const float*)d_in[17];
    const float *Wpf2 = (const float*)d_in[18], *bpf2 = (const float*)d_in[19];
    const float *Wd2  = (const float*)d_in[20], *bd2  = (const float*)d_in[21];
    const float *Wuf2 = (const float*)d_in[22], *buf2 = (const float*)d_in[23];
    const float *W10  = (const float*)d_in[24], *b10  = (const float*)d_in[25];
    const float *Wpf1 = (const float*)d_in[26], *bpf1 = (const float*)d_in[27];
    const float *Wd1  = (const float*)d_in[28], *bd1  = (const float*)d_in[29];
    const float *Wuf1 = (const float*)d_in[30], *buf1 = (const float*)d_in[31];
    const float *W00  = (const float*)d_in[32], *b00  = (const float*)d_in[33];
    const float *Wpf0 = (const float*)d_in[34], *bpf0 = (const float*)d_in[35];
    const float *Wd0  = (const float*)d_in[36], *bd0  = (const float*)d_in[37];

    const size_t S128 = 128u * 128 * 128, S64 = 64u * 64 * 64, S32 = 32u * 32 * 32, S16 = 16u * 16 * 16;

    char* base = (char*)d_ws;
    size_t off = 0;
    auto AF = [&](size_t n) { off = (off + 255) & ~(size_t)255; float* p = (float*)(base + off); off += n * 4; return p; };
    auto AH = [&](size_t n) { off = (off + 255) & ~(size_t)255; ushort* p = (ushort*)(base + off); off += n * 2; return p; };

    ushort* wp1aa = AH(13824); ushort* wp1b = AH(13824);
    ushort* wp2a  = AH(27648); ushort* wp2aa = AH(27648); ushort* wp2b = AH(27648);
    ushort* wp20  = AH(110592); ushort* wp10 = AH(138240); ushort* wp00 = AH(193536);
    ushort* wpf2  = AH(13824);  ushort* wpf1 = AH(13824);  ushort* wpf0 = AH(13824);
    ushort* wpd_uf1 = AH(131072);
    float* wt_uf2 = AF(6144);
    float* wt_d2  = AF(576);    float* wt_d1 = AF(576);    float* wt_d0 = AF(576);
    float* stats = AF(1024);
    ushort* zbuf = AH(1024);    // zero guard for OOB global_load_lds sources
    float* im12 = AF(8 * S64);
    float* im1 = im12; float* im2 = im12 + 4 * S64;
    float* im1clf = AF(4 * S64);     // [S64][4] ch-last fp32 (costvol E f1)
    float* warp0clf = AF(4 * S64);   // [S64][4] ch-last fp32 (costvol E f2)
    float* c11clf = AF(16 * S32);    // [S32][16] ch-last fp32 (costvol D f1)
    float* warp1clf = AF(16 * S32);  // [S32][16] ch-last fp32 (costvol D f2)
    float* A1   = AF(32 * S32); ushort* A1cl = AH(2 * S32 * 32);
    float* B1   = AF(32 * S32); ushort* B1cl = AH(2 * S32 * 32);
    float* c1121 = AF(32 * S32); ushort* c1121cl = AH(2 * S32 * 32);
    float* c11 = c1121; float* c21 = c1121 + 16 * S32;
    float* A2   = AF(64 * S16); ushort* A2cl = AH(2 * S16 * 32);
    float* B2   = AF(64 * S16); ushort* B2cl = AH(2 * S16 * 32);
    ushort* cv2cl = AH(S16 * 128);
    float* x20  = AF(32 * S16); ushort* x20cl = AH(S16 * 32);
    float* flow2 = AF(3 * S16); float* upflow2 = AF(3 * S32);
    ushort* x147cl = AH(S32 * 160);
    float* x10  = AF(32 * S32); ushort* x10cl = AH(S32 * 32);
    float* flow1 = AF(3 * S32); float* upflow1 = AF(3 * S64);
    ushort* x196cl = AH(S64 * 224);
    float* x00  = AF(32 * S64); float* flow0 = AF(3 * S64);

    ushort* x00cl = x196cl;            // overlay: live only after W00 consumed x196cl

    float* outF = (float*)d_out;
    float* c22o = outF + 3 * S128;
    float* c12o = c22o + 32 * S16;

    // stats layout: batched pairs contiguous
    const int ST_IM=0, ST_A1=8, ST_B1=40, ST_C1=72, ST_A2=104, ST_B2=168, ST_C2=232,
              ST_X20=296, ST_X10=328, ST_X00=360;
    auto SP = [&](int o) { return stats + 2 * o; };
    hipMemsetAsync(stats, 0, 4096, st);
    hipMemsetAsync(zbuf, 0, 2048, st);

    WTab tab; int nb = 0, ti = 0;
    auto addw = [&](const float* s, void* d, int kind, int Cin, int COUT, int KC, int coutr) {
        int tot = (kind == 0) ? 27 * KC * (COUT >> 4) * 512
                 : (kind == 1) ? 8 * 8 * KC * 512 : Cin * COUT * 64;
        tab.t[ti] = WTask{s, d, kind, Cin, COUT, KC, coutr, nb};
        nb += DIVUP(tot, 256); ti++;
    };
    addw(W1aa, wp1aa, 0, 16, 16, 1, 16);
    addw(W1b,  wp1b,  0, 16, 16, 1, 16);
    addw(W2a,  wp2a,  0, 16, 32, 1, 32);
    addw(W2aa, wp2aa, 0, 32, 32, 1, 32);
    addw(W2b,  wp2b,  0, 32, 32, 1, 32);
    addw(W20,  wp20,  0, 125, 32, 4, 32);
    addw(W10,  wp10,  0, 147, 32, 5, 32);
    addw(W00,  wp00,  0, 196, 32, 7, 32);
    addw(Wpf2, wpf2,  0, 32, 16, 1, 3);
    addw(Wpf1, wpf1,  0, 32, 16, 1, 3);
    addw(Wpf0, wpf0,  0, 32, 16, 1, 3);
    addw(Wuf1, wpd_uf1, 1, 32, 64, 4, 64);
    addw(Wuf2, wt_uf2, 2, 32, 3, 0, 3);
    addw(Wd2,  wt_d2,  2, 3, 3, 0, 3);
    addw(Wd1,  wt_d1,  2, 3, 3, 0, 3);
    addw(Wd0,  wt_d0,  2, 3, 3, 0, 3);
    tab.n = ti;
    wprep_k<<<nb, 256, 0, st>>>(tab);

    // ---- stage A (batched: b0=target->im1, b1=atlas->im2) ----
    conv3x3_k<4, 2><<<dim3(8, 8, 32), 256, 0, st>>>(target, atlas, W_ct, b_ct, im12,
                                                    SP(ST_IM), 1, 128, 128, 128,
                                                    16, (long)(4 * S64), 4);
    apply(st, im12, 8, S64, SP(ST_IM), nullptr, 0, 4, 0, im1clf, 4, 4);

    // ---- stage B (batched) ----
    // W1a: Cin=4 real channels -> fp32 direct conv from im12 (CP=32 bf16 path was
    // 8x byte-padded and 87%-zero MFMA K). Reads im12 fp32 (normalized in-place).
    conv3x3_k<16, 2><<<dim3(4, 4, 16), 256, 0, st>>>(im1, im2, W1a, b1a, A1,
                                                     SP(ST_A1), 4, 64, 64, 64,
                                                     8, (long)(16 * S32), 16);
    apply(st, A1, 32, S32, SP(ST_A1), A1cl, 32, 16, (long)(S32 * 32));
    mconv_k<32, 1, 1, 2, 16><<<dim3(4, 4, 32), 128, 0, st>>>(A1cl, wp1aa, b1aa, B1, SP(ST_B1),
        zbuf, 32, 32, 32, 16, (long)(S32 * 32), (long)(16 * S32), 16);
    apply(st, B1, 32, S32, SP(ST_B1), B1cl, 32, 16, (long)(S32 * 32));
    mconv_k<32, 1, 1, 2, 16><<<dim3(4, 4, 32), 128, 0, st>>>(B1cl, wp1b, b1b, c1121, SP(ST_C1),
        zbuf, 32, 32, 32, 16, (long)(S32 * 32), (long)(16 * S32), 16);
    apply(st, c1121, 32, S32, SP(ST_C1), c1121cl, 32, 16, (long)(S32 * 32), c11clf, 16, 16);

    // ---- stage C (batched) ----
    mconv_k<32, 2, 2, 4, 32><<<dim3(4, 4, 8), 256, 0, st>>>(c1121cl, wp2a, b2a, A2, SP(ST_A2),
        zbuf, 32, 32, 32, 4, (long)(S32 * 32), (long)(32 * S16), 32);
    apply(st, A2, 64, S16, SP(ST_A2), A2cl, 32, 32, (long)(S16 * 32));
    mconv_k<32, 2, 1, 2, 32><<<dim3(2, 2, 16), 128, 0, st>>>(A2cl, wp2aa, b2aa, B2, SP(ST_B2),
        zbuf, 16, 16, 16, 8, (long)(S16 * 32), (long)(32 * S16), 32);
    apply(st, B2, 64, S16, SP(ST_B2), B2cl, 32, 32, (long)(S16 * 32));
    mconv_k<32, 2, 1, 2, 32><<<dim3(2, 2, 16), 128, 0, st>>>(B2cl, wp2b, b2b, c12o, SP(ST_C2),
        zbuf, 16, 16, 16, 8, (long)(S16 * 32), (long)(c22o - c12o), 32);
    apply(st, c12o, 32, S16, SP(ST_C2), nullptr, 0, 32, 0);
    apply(st, c22o, 32, S16, SP(ST_C2 + 32), nullptr, 0, 32, 0);

    costvolw_k<32, 128, 0><<<DIVUP(S16, 4), 256, 0, st>>>(c12o, c22o, cv2cl, 16, 16, 16);
    mconv_k<128, 2, 1, 2, 32><<<dim3(2, 2, 8), 128, 0, st>>>(cv2cl, wp20, b20, x20, SP(ST_X20),
        zbuf, 16, 16, 16, 8, 0, 0, 0);
    apply(st, x20, 32, S16, SP(ST_X20), x20cl, 32, 32, 0);
    mconv_k<32, 1, 1, 2, 3><<<dim3(2, 2, 8), 128, 0, st>>>(x20cl, wpf2, bpf2, flow2, nullptr,
        zbuf, 16, 16, 16, 8, 0, 0, 0);
    dctn_k<3><<<DIVUP(8 * S16, 256), 256, 0, st>>>(flow2, wt_d2, bd2, upflow2, x147cl, 141, 160, 16);
    dctn_k<32><<<DIVUP(8 * S16, 256), 256, 0, st>>>(x20, wt_uf2, buf2, nullptr, x147cl, 144, 160, 16);

    // ---- stage D ----
    warpcl_k<16><<<DIVUP(S32, 256), 256, 0, st>>>(c21, upflow2, warp1clf, 32, 32, 32);
    costvolcl_k<16, 160, 2><<<(unsigned)(S32 / 8), 256, 0, st>>>(c11clf, warp1clf, x147cl,
                                                                 32, 32, 32);
    mconv_k<160, 2, 1, 2, 32><<<dim3(4, 4, 16), 128, 0, st>>>(x147cl, wp10, b10, x10, SP(ST_X10),
        zbuf, 32, 32, 32, 16, 0, 0, 0);
    apply(st, x10, 32, S32, SP(ST_X10), x10cl, 32, 32, 0);
    mconv_k<32, 1, 1, 2, 3><<<dim3(4, 4, 16), 128, 0, st>>>(x10cl, wpf1, bpf1, flow1, nullptr,
        zbuf, 32, 32, 32, 16, 0, 0, 0);
    dctn_k<3><<<DIVUP(8 * S32, 256), 256, 0, st>>>(flow1, wt_d1, bd1, upflow1, x196cl, 129, 224, 32);
    mdeconv_k<4><<<dim3(4, 4, 64), 256, 0, st>>>(x10cl, wpd_uf1, buf1, x196cl, 132, 224, 32);

    // ---- stage E ----
    warpcl_k<4><<<DIVUP(S64, 256), 256, 0, st>>>(im2, upflow1, warp0clf, 64, 64, 64);
    costvolcl_k<4, 224, 4><<<(unsigned)(S64 / 16), 256, 0, st>>>(im1clf, warp0clf, x196cl,
                                                                 64, 64, 64);
    mconv_k<224, 2, 1, 4, 32><<<dim3(8, 8, 16), 256, 0, st>>>(x196cl, wp00, b00, x00, SP(ST_X00),
        zbuf, 64, 64, 64, 16, 0, 0, 0);
    apply(st, x00, 32, S64, SP(ST_X00), x00cl, 32, 32, 0);
    mconv_k<32, 1, 1, 4, 3><<<dim3(8, 8, 16), 256, 0, st>>>(x00cl, wpf0, bpf0, flow0, nullptr,
        zbuf, 64, 64, 64, 16, 0, 0, 0);
    dctn_k<3><<<DIVUP(S128, 256), 256, 0, st>>>(flow0, wt_d0, bd0, outF, nullptr, 0, 0, 64);
}